// Round 8
// baseline (624.367 us; speedup 1.0000x reference)
//
#include <hip/hip_runtime.h>

#define NN 100000
#define NE 1600000
#define FD 128
#define CO 10
#define BN_EPS 1e-5f
#define SCAN_B 1024
#define SCAN_NB ((NN + SCAN_B - 1) / SCAN_B)   // 98
#define NBUK ((NN + 127) / 128)                // 782 buckets of 128 nodes
#define BCAP 3072
#define SEGE 4096
#define NSEG ((NE + SEGE - 1) / SEGE)          // 391
#define CHN 4                                  // feature chunks
#define CHW 32                                 // feats per chunk (64 B bf16)
#define GBLK ((NN + 3) / 4)                    // 25000 gather blocks per chunk

typedef __attribute__((ext_vector_type(8))) short short8;
typedef __attribute__((ext_vector_type(4))) float f32x4;

__device__ __forceinline__ unsigned short f2bf(float f) {
  unsigned int u = __builtin_bit_cast(unsigned int, f);
  u = (u + 0x7FFFu + ((u >> 16) & 1u)) >> 16;
  return (unsigned short)u;
}
__device__ __forceinline__ float bf2f(unsigned short h) {
  unsigned int u = ((unsigned int)h) << 16;
  return __builtin_bit_cast(float, u);
}
__device__ __forceinline__ float blo(unsigned int u) {
  return __builtin_bit_cast(float, u << 16);
}
__device__ __forceinline__ float bhi(unsigned int u) {
  return __builtin_bit_cast(float, u & 0xFFFF0000u);
}

// ---------------- bucket pass: LDS-aggregated counting sort by dst>>7 -------
__global__ __launch_bounds__(256) void k_bucket2(const int* __restrict__ src,
                                                 const int* __restrict__ dst,
                                                 int* __restrict__ bcnt,
                                                 uint2* __restrict__ buck) {
  __shared__ int hist[NBUK];
  __shared__ int base[NBUK];
  int b = blockIdx.x, t = threadIdx.x;
  for (int i = t; i < NBUK; i += 256) hist[i] = 0;
  __syncthreads();
  int e0 = b * SEGE, e1 = min(e0 + SEGE, NE);
  for (int e = e0 + t; e < e1; e += 256) {
    atomicAdd(&hist[dst[e] >> 7], 1);
  }
  __syncthreads();
  for (int i = t; i < NBUK; i += 256) {
    int h = hist[i];
    base[i] = h ? atomicAdd(&bcnt[i * 16], h) : 0;
  }
  __syncthreads();
  for (int e = e0 + t; e < e1; e += 256) {
    int s = src[e], d = dst[e];
    int bk = d >> 7;
    int slot = atomicAdd(&base[bk], 1);
    buck[(size_t)bk * BCAP + slot] = make_uint2((unsigned)s, (unsigned)d);
  }
}

// ---------------- per-bucket degree count + fused dinv ----------------
__global__ __launch_bounds__(256) void k_bdeg(const int* __restrict__ bcnt,
                                              const uint2* __restrict__ buck,
                                              int* __restrict__ deg_i,
                                              float* __restrict__ dinv) {
  __shared__ int cnt[128];
  int b = blockIdx.x, t = threadIdx.x;
  if (t < 128) cnt[t] = 0;
  __syncthreads();
  int nb = bcnt[b * 16];
  const uint2* bp = buck + (size_t)b * BCAP;
  for (int i = t; i < nb; i += 256) atomicAdd(&cnt[bp[i].y & 127], 1);
  __syncthreads();
  int node = b * 128 + t;
  if (t < 128 && node < NN) {
    int dg = cnt[t];
    deg_i[node] = dg;
    dinv[node] = rsqrtf((float)dg + 1.0f);
  }
}

// ---------------- exclusive scan over deg_i -> row_start ----------------
__global__ __launch_bounds__(256) void k_scan_partial(const int* __restrict__ deg_i,
                                                      int* __restrict__ blocksum) {
  __shared__ int lds[256];
  int b = blockIdx.x, t = threadIdx.x;
  int base = b * SCAN_B + t * 4;
  int s = 0;
#pragma unroll
  for (int i = 0; i < 4; ++i) {
    int idx = base + i;
    s += (idx < NN) ? deg_i[idx] : 0;
  }
  lds[t] = s;
  __syncthreads();
  for (int off = 128; off > 0; off >>= 1) {
    if (t < off) lds[t] += lds[t + off];
    __syncthreads();
  }
  if (t == 0) blocksum[b] = lds[0];
}

__global__ void k_scan_block(int* __restrict__ blocksum) {
  __shared__ int lds[128];
  int t = threadIdx.x;
  int v = (t < SCAN_NB) ? blocksum[t] : 0;
  lds[t] = v;
  __syncthreads();
  for (int off = 1; off < 128; off <<= 1) {
    int add = (t >= off) ? lds[t - off] : 0;
    __syncthreads();
    lds[t] += add;
    __syncthreads();
  }
  if (t < SCAN_NB) blocksum[t] = lds[t] - v;
}

__global__ __launch_bounds__(256) void k_scan_final(const int* __restrict__ deg_i,
                                                    const int* __restrict__ blocksum,
                                                    int* __restrict__ row_start) {
  __shared__ int lds[256];
  int b = blockIdx.x, t = threadIdx.x;
  int base = b * SCAN_B + t * 4;
  int v[4];
  int s = 0;
#pragma unroll
  for (int i = 0; i < 4; ++i) {
    int idx = base + i;
    v[i] = (idx < NN) ? deg_i[idx] : 0;
    s += v[i];
  }
  lds[t] = s;
  __syncthreads();
  int mine = s;
  for (int off = 1; off < 256; off <<= 1) {
    int add = (t >= off) ? lds[t - off] : 0;
    __syncthreads();
    lds[t] += add;
    __syncthreads();
  }
  int run = lds[t] - mine + blocksum[b];
#pragma unroll
  for (int i = 0; i < 4; ++i) {
    int idx = base + i;
    if (idx < NN) {
      row_start[idx] = run;
      run += v[i];
    }
  }
  if (b == 0 && t == 0) row_start[NN] = NE;
}

// ---------------- place pass: bucket -> CSR ----------------
__global__ __launch_bounds__(256) void k_place(const int* __restrict__ bcnt,
                                               const uint2* __restrict__ buck,
                                               const int* __restrict__ row_start,
                                               int* __restrict__ csr_src) {
  __shared__ int cnt[128];
  int b = blockIdx.x, t = threadIdx.x;
  if (t < 128) cnt[t] = 0;
  __syncthreads();
  int nb = bcnt[b * 16];
  const uint2* bp = buck + (size_t)b * BCAP;
  for (int i = t; i < nb; i += 256) {
    uint2 sd = bp[i];
    int d = (int)sd.y;
    int l = atomicAdd(&cnt[d & 127], 1);
    csr_src[row_start[d] + l] = (int)sd.x;
  }
}

// ---------------- BN constants ----------------
__global__ void k_prep_bn(const float* __restrict__ b, const float* __restrict__ g,
                          const float* __restrict__ be, const float* __restrict__ m,
                          const float* __restrict__ v, float* __restrict__ sc,
                          float* __restrict__ sh) {
  int f = threadIdx.x;
  if (f < FD) {
    float s = g[f] * rsqrtf(v[f] + BN_EPS);
    sc[f] = s;
    sh[f] = (b[f] - m[f]) * s + be[f];
  }
}

// ---------------- MFMA GEMM 128x128 (bf16x3 split) -> pre-scaled bf16 chunks --
// Hbs[c][row][w] = bf16( (X@W)[row, c*32+w] * dinv[row] )
template <bool ROWMAJOR>
__global__ __launch_bounds__(256) void k_gemm128_mfma(const float* __restrict__ X,
                                                      const float* __restrict__ W,
                                                      const float* __restrict__ dinv,
                                                      unsigned short* __restrict__ Hbs,
                                                      int nrows) {
  __shared__ short bhi_s[FD * FD];  // 32 KB
  __shared__ short blo_s[FD * FD];  // 32 KB
  int tid = threadIdx.x;
  for (int i = tid; i < FD * FD; i += 256) {
    int k = i >> 7, n = i & 127;
    float w = W[i];
    unsigned short h = f2bf(w);
    unsigned short l = f2bf(w - bf2f(h));
    int idx = ((((k >> 5) * 8) + (n >> 4)) * 64 + ((k >> 3) & 3) * 16 + (n & 15)) * 8 + (k & 7);
    bhi_s[idx] = (short)h;
    blo_s[idx] = (short)l;
  }

  int lane = tid & 63, wv = tid >> 6;
  int lg = lane >> 4, li = lane & 15;
  int wr0 = blockIdx.x * 64 + wv * 16;
  int row = wr0 + li;
  bool ok = row < nrows;

  short8 ahi[4], alo[4];
#pragma unroll
  for (int ks = 0; ks < 4; ++ks) {
    if (ok) {
      const float* xp = ROWMAJOR ? (X + (size_t)row * FD + ks * 32 + lg * 8)
                                 : (X + ((size_t)ks * NN + row) * CHW + lg * 8);
      float4 v0 = *(const float4*)xp;
      float4 v1 = *(const float4*)(xp + 4);
      float f[8] = {v0.x, v0.y, v0.z, v0.w, v1.x, v1.y, v1.z, v1.w};
#pragma unroll
      for (int j = 0; j < 8; ++j) {
        unsigned short h = f2bf(f[j]);
        ahi[ks][j] = (short)h;
        alo[ks][j] = (short)f2bf(f[j] - bf2f(h));
      }
    } else {
#pragma unroll
      for (int j = 0; j < 8; ++j) { ahi[ks][j] = 0; alo[ks][j] = 0; }
    }
  }
  __syncthreads();

  int rb = wr0 + lg * 4;
  float dvr[4];
#pragma unroll
  for (int r = 0; r < 4; ++r) dvr[r] = (rb + r < nrows) ? dinv[rb + r] : 0.f;

#pragma unroll
  for (int nt = 0; nt < 8; ++nt) {
    f32x4 acc = {0.f, 0.f, 0.f, 0.f};
#pragma unroll
    for (int ks = 0; ks < 4; ++ks) {
      int bidx = ((ks * 8 + nt) * 64 + lane) * 8;
      short8 bh = *(const short8*)&bhi_s[bidx];
      short8 bl = *(const short8*)&blo_s[bidx];
      acc = __builtin_amdgcn_mfma_f32_16x16x32_bf16(ahi[ks], bh, acc, 0, 0, 0);
      acc = __builtin_amdgcn_mfma_f32_16x16x32_bf16(alo[ks], bh, acc, 0, 0, 0);
      acc = __builtin_amdgcn_mfma_f32_16x16x32_bf16(ahi[ks], bl, acc, 0, 0, 0);
    }
    // C/D: col = lane&15, row = (lane>>4)*4 + reg   [m89-verified]
    int col = nt * 16 + li;
    int cc = col >> 5, w = col & 31;
#pragma unroll
    for (int r = 0; r < 4; ++r) {
      if (rb + r < nrows)
        Hbs[((size_t)cc * NN + rb + r) * CHW + w] = f2bf(acc[r] * dvr[r]);
    }
  }
}

// ---------------- chunked node-parallel gather (+BN+ReLU) ----------------
// One wave per (node, chunk); 4 edge-groups of 16 lanes; self = extra row.
// acc = (sum of pre-scaled rows) * dinv[node].
template <bool BN>
__global__ __launch_bounds__(256) void k_gather32(const int* __restrict__ row_start,
                                                  const int* __restrict__ csr_src,
                                                  const float* __restrict__ dinv,
                                                  const unsigned short* __restrict__ Hbs,
                                                  const float* __restrict__ sc,
                                                  const float* __restrict__ sh,
                                                  float* __restrict__ AGG) {
  unsigned bid = blockIdx.x;
  int c = bid / GBLK;
  int nid = (bid - c * GBLK) * 4 + (threadIdx.x >> 6);
  if (nid >= NN) return;
  int lane = threadIdx.x & 63;
  int g = lane >> 4, li = lane & 15;
  const unsigned int* Hc = (const unsigned int*)(Hbs + (size_t)c * NN * CHW);
  int beg = row_start[nid], end = row_start[nid + 1];
  float ax = 0.f, ay = 0.f, cx = 0.f, cy = 0.f;
  int e = beg + g;
  for (; e + 4 < end; e += 8) {
    int s0 = csr_src[e], s1 = csr_src[e + 4];
    unsigned int u0 = Hc[(size_t)s0 * 16 + li];
    unsigned int u1 = Hc[(size_t)s1 * 16 + li];
    ax += blo(u0); ay += bhi(u0);
    cx += blo(u1); cy += bhi(u1);
  }
  if (e < end) {
    unsigned int u0 = Hc[(size_t)csr_src[e] * 16 + li];
    ax += blo(u0); ay += bhi(u0);
  }
  if (g == 0) {  // self-loop row
    unsigned int u = Hc[(size_t)nid * 16 + li];
    ax += blo(u); ay += bhi(u);
  }
  ax += cx; ay += cy;
  ax += __shfl_xor(ax, 16); ay += __shfl_xor(ay, 16);
  ax += __shfl_xor(ax, 32); ay += __shfl_xor(ay, 32);
  float dv = dinv[nid];
  ax *= dv; ay *= dv;
  if (BN) {
    int f = c * CHW + li * 2;
    ax = fmaxf(fmaf(ax, sc[f], sh[f]), 0.f);
    ay = fmaxf(fmaf(ay, sc[f + 1], sh[f + 1]), 0.f);
  }
  if (lane < 16) {
    float2 o;
    o.x = ax; o.y = ay;
    ((float2*)(AGG + ((size_t)c * NN + nid) * CHW))[li] = o;
  }
}

// ---------------- output GEMM 128->10 (chunked input) ----------------
__global__ __launch_bounds__(256) void k_gemm_out(const float* __restrict__ X,
                                                  const float* __restrict__ W3,
                                                  float* __restrict__ H3, int nrows) {
  __shared__ float ws[FD * 16];
  int tid = threadIdx.x;
  for (int i = tid; i < FD * 16; i += 256) {
    int k = i >> 4, c = i & 15;
    ws[i] = (c < CO) ? W3[k * CO + c] : 0.f;
  }
  __syncthreads();
  int grp = tid >> 4;
  int c = tid & 15;
  int r = blockIdx.x * 16 + grp;
  if (r >= nrows) return;
  float acc = 0.f;
#pragma unroll
  for (int ck = 0; ck < CHN; ++ck) {
    const float* x = X + ((size_t)ck * NN + r) * CHW;
#pragma unroll
    for (int w = 0; w < CHW; w += 4) {
      float4 xv = *(const float4*)&x[w];
      int k = ck * CHW + w;
      acc += xv.x * ws[(k + 0) * 16 + c];
      acc += xv.y * ws[(k + 1) * 16 + c];
      acc += xv.z * ws[(k + 2) * 16 + c];
      acc += xv.w * ws[(k + 3) * 16 + c];
    }
  }
  if (c < CO) H3[(size_t)r * CO + c] = acc;
}

// ---------------- gather 10 feat, fused self-loop + bias, writes out --------
__global__ __launch_bounds__(256) void k_gather10(const int* __restrict__ row_start,
                                                  const int* __restrict__ csr_src,
                                                  const float* __restrict__ dinv,
                                                  const float* __restrict__ H3,
                                                  const float* __restrict__ b3,
                                                  float* __restrict__ out) {
  int node = blockIdx.x * 16 + (threadIdx.x >> 4);
  if (node >= NN) return;
  int c = threadIdx.x & 15;
  int beg = row_start[node], end = row_start[node + 1];
  float dv = dinv[node];
  float acc = 0.f;
  if (c < CO) acc = H3[(size_t)node * CO + c] * (dv * dv);
  for (int e = beg; e < end; ++e) {
    int s = csr_src[e];
    float cf = dinv[s] * dv;
    if (c < CO) acc = fmaf(H3[(size_t)s * CO + c], cf, acc);
  }
  if (c < CO) out[(size_t)node * CO + c] = acc + b3[c];
}

// ---------------- launch ----------------
extern "C" void kernel_launch(void* const* d_in, const int* in_sizes, int n_in,
                              void* d_out, int out_size, void* d_ws, size_t ws_size,
                              hipStream_t stream) {
  const float* x = (const float*)d_in[0];
  const int* src = (const int*)d_in[1];
  const int* dst = (const int*)d_in[2];
  const float* W1 = (const float*)d_in[3];
  const float* b1 = (const float*)d_in[4];
  const float* g1 = (const float*)d_in[5];
  const float* be1 = (const float*)d_in[6];
  const float* m1 = (const float*)d_in[7];
  const float* v1 = (const float*)d_in[8];
  const float* W2 = (const float*)d_in[9];
  const float* b2 = (const float*)d_in[10];
  const float* g2 = (const float*)d_in[11];
  const float* be2 = (const float*)d_in[12];
  const float* m2 = (const float*)d_in[13];
  const float* v2 = (const float*)d_in[14];
  const float* W3 = (const float*)d_in[15];
  const float* b3 = (const float*)d_in[16];
  float* out = (float*)d_out;

  char* wsb = (char*)d_ws;
  int* deg_i = (int*)wsb;                     wsb += NN * 4;
  int* row_start = (int*)wsb;                 wsb += (NN + 1) * 4;
  int* bcnt = (int*)wsb;                      wsb += (size_t)NBUK * 16 * 4;
  int* blocksum = (int*)wsb;                  wsb += 128 * 4;
  float* dinv = (float*)wsb;                  wsb += NN * 4;
  float* sc1 = (float*)wsb;                   wsb += FD * 4;
  float* sh1 = (float*)wsb;                   wsb += FD * 4;
  float* sc2 = (float*)wsb;                   wsb += FD * 4;
  float* sh2 = (float*)wsb;                   wsb += FD * 4;
  int* csr_src = (int*)wsb;                   wsb += (size_t)NE * 4;
  uint2* buck = (uint2*)wsb;                  wsb += (size_t)NBUK * BCAP * 8;
  float* AGG = (float*)wsb;                   wsb += (size_t)NN * FD * 4;   // chunked [4][N][32]
  unsigned short* Hbs = (unsigned short*)wsb; wsb += (size_t)NN * FD * 2;   // chunked [4][N][32]
  float* H3 = (float*)Hbs;  // layer-3 reuse (Hbs dead after layer-2 gather)

  hipMemsetAsync(bcnt, 0, (size_t)NBUK * 16 * 4, stream);
  k_bucket2<<<NSEG, 256, 0, stream>>>(src, dst, bcnt, buck);
  k_bdeg<<<NBUK, 256, 0, stream>>>(bcnt, buck, deg_i, dinv);
  k_scan_partial<<<SCAN_NB, 256, 0, stream>>>(deg_i, blocksum);
  k_scan_block<<<1, 128, 0, stream>>>(blocksum);
  k_scan_final<<<SCAN_NB, 256, 0, stream>>>(deg_i, blocksum, row_start);
  k_place<<<NBUK, 256, 0, stream>>>(bcnt, buck, row_start, csr_src);
  k_prep_bn<<<1, 128, 0, stream>>>(b1, g1, be1, m1, v1, sc1, sh1);
  k_prep_bn<<<1, 128, 0, stream>>>(b2, g2, be2, m2, v2, sc2, sh2);

  int gemm_blocks = (NN + 63) / 64;
  int gat_blocks = CHN * GBLK;   // 100000, chunk-major -> temporal L2 locality

  // layer 1
  k_gemm128_mfma<true><<<gemm_blocks, 256, 0, stream>>>(x, W1, dinv, Hbs, NN);
  k_gather32<true><<<gat_blocks, 256, 0, stream>>>(row_start, csr_src, dinv,
                                                   Hbs, sc1, sh1, AGG);
  // layer 2
  k_gemm128_mfma<false><<<gemm_blocks, 256, 0, stream>>>(AGG, W2, dinv, Hbs, NN);
  k_gather32<true><<<gat_blocks, 256, 0, stream>>>(row_start, csr_src, dinv,
                                                   Hbs, sc2, sh2, AGG);
  // layer 3
  k_gemm_out<<<(NN + 15) / 16, 256, 0, stream>>>(AGG, W3, H3, NN);
  k_gather10<<<(NN + 15) / 16, 256, 0, stream>>>(row_start, csr_src, dinv,
                                                 H3, b3, out);
}

// Round 9
// 438.437 us; speedup vs baseline: 1.4241x; 1.4241x over previous
//
#include <hip/hip_runtime.h>

#define NN 100000
#define NE 1600000
#define FD 128
#define CO 10
#define BN_EPS 1e-5f
#define SCAN_B 1024
#define SCAN_NB ((NN + SCAN_B - 1) / SCAN_B)   // 98
#define NBUK ((NN + 127) / 128)                // 782 buckets of 128 nodes
#define BCAP 3072
#define SEGE 4096
#define NSEG ((NE + SEGE - 1) / SEGE)          // 391

typedef __attribute__((ext_vector_type(8))) short short8;
typedef __attribute__((ext_vector_type(4))) float f32x4;

__device__ __forceinline__ unsigned short f2bf(float f) {
  unsigned int u = __builtin_bit_cast(unsigned int, f);
  u = (u + 0x7FFFu + ((u >> 16) & 1u)) >> 16;
  return (unsigned short)u;
}
__device__ __forceinline__ float bf2f(unsigned short h) {
  unsigned int u = ((unsigned int)h) << 16;
  return __builtin_bit_cast(float, u);
}
__device__ __forceinline__ float blo(unsigned int u) {
  return __builtin_bit_cast(float, u << 16);
}
__device__ __forceinline__ float bhi(unsigned int u) {
  return __builtin_bit_cast(float, u & 0xFFFF0000u);
}

// ---------------- bucket pass: LDS-aggregated counting sort by dst>>7 -------
__global__ __launch_bounds__(256) void k_bucket2(const int* __restrict__ src,
                                                 const int* __restrict__ dst,
                                                 int* __restrict__ bcnt,
                                                 uint2* __restrict__ buck) {
  __shared__ int hist[NBUK];
  __shared__ int base[NBUK];
  int b = blockIdx.x, t = threadIdx.x;
  for (int i = t; i < NBUK; i += 256) hist[i] = 0;
  __syncthreads();
  int e0 = b * SEGE, e1 = min(e0 + SEGE, NE);
  for (int e = e0 + t; e < e1; e += 256) {
    atomicAdd(&hist[dst[e] >> 7], 1);
  }
  __syncthreads();
  for (int i = t; i < NBUK; i += 256) {
    int h = hist[i];
    base[i] = h ? atomicAdd(&bcnt[i * 16], h) : 0;
  }
  __syncthreads();
  for (int e = e0 + t; e < e1; e += 256) {
    int s = src[e], d = dst[e];
    int bk = d >> 7;
    int slot = atomicAdd(&base[bk], 1);
    buck[(size_t)bk * BCAP + slot] = make_uint2((unsigned)s, (unsigned)d);
  }
}

// ---------------- per-bucket degree count + fused dinv ----------------
__global__ __launch_bounds__(256) void k_bdeg(const int* __restrict__ bcnt,
                                              const uint2* __restrict__ buck,
                                              int* __restrict__ deg_i,
                                              float* __restrict__ dinv) {
  __shared__ int cnt[128];
  int b = blockIdx.x, t = threadIdx.x;
  if (t < 128) cnt[t] = 0;
  __syncthreads();
  int nb = bcnt[b * 16];
  const uint2* bp = buck + (size_t)b * BCAP;
  for (int i = t; i < nb; i += 256) atomicAdd(&cnt[bp[i].y & 127], 1);
  __syncthreads();
  int node = b * 128 + t;
  if (t < 128 && node < NN) {
    int dg = cnt[t];
    deg_i[node] = dg;
    dinv[node] = rsqrtf((float)dg + 1.0f);
  }
}

// ---------------- exclusive scan over deg_i -> row_start ----------------
__global__ __launch_bounds__(256) void k_scan_partial(const int* __restrict__ deg_i,
                                                      int* __restrict__ blocksum) {
  __shared__ int lds[256];
  int b = blockIdx.x, t = threadIdx.x;
  int base = b * SCAN_B + t * 4;
  int s = 0;
#pragma unroll
  for (int i = 0; i < 4; ++i) {
    int idx = base + i;
    s += (idx < NN) ? deg_i[idx] : 0;
  }
  lds[t] = s;
  __syncthreads();
  for (int off = 128; off > 0; off >>= 1) {
    if (t < off) lds[t] += lds[t + off];
    __syncthreads();
  }
  if (t == 0) blocksum[b] = lds[0];
}

__global__ void k_scan_block(int* __restrict__ blocksum) {
  __shared__ int lds[128];
  int t = threadIdx.x;
  int v = (t < SCAN_NB) ? blocksum[t] : 0;
  lds[t] = v;
  __syncthreads();
  for (int off = 1; off < 128; off <<= 1) {
    int add = (t >= off) ? lds[t - off] : 0;
    __syncthreads();
    lds[t] += add;
    __syncthreads();
  }
  if (t < SCAN_NB) blocksum[t] = lds[t] - v;
}

__global__ __launch_bounds__(256) void k_scan_final(const int* __restrict__ deg_i,
                                                    const int* __restrict__ blocksum,
                                                    int* __restrict__ row_start) {
  __shared__ int lds[256];
  int b = blockIdx.x, t = threadIdx.x;
  int base = b * SCAN_B + t * 4;
  int v[4];
  int s = 0;
#pragma unroll
  for (int i = 0; i < 4; ++i) {
    int idx = base + i;
    v[i] = (idx < NN) ? deg_i[idx] : 0;
    s += v[i];
  }
  lds[t] = s;
  __syncthreads();
  int mine = s;
  for (int off = 1; off < 256; off <<= 1) {
    int add = (t >= off) ? lds[t - off] : 0;
    __syncthreads();
    lds[t] += add;
    __syncthreads();
  }
  int run = lds[t] - mine + blocksum[b];
#pragma unroll
  for (int i = 0; i < 4; ++i) {
    int idx = base + i;
    if (idx < NN) {
      row_start[idx] = run;
      run += v[i];
    }
  }
  if (b == 0 && t == 0) row_start[NN] = NE;
}

// ---------------- place pass: bucket -> CSR ----------------
__global__ __launch_bounds__(256) void k_place(const int* __restrict__ bcnt,
                                               const uint2* __restrict__ buck,
                                               const int* __restrict__ row_start,
                                               int* __restrict__ csr_src) {
  __shared__ int cnt[128];
  int b = blockIdx.x, t = threadIdx.x;
  if (t < 128) cnt[t] = 0;
  __syncthreads();
  int nb = bcnt[b * 16];
  const uint2* bp = buck + (size_t)b * BCAP;
  for (int i = t; i < nb; i += 256) {
    uint2 sd = bp[i];
    int d = (int)sd.y;
    int l = atomicAdd(&cnt[d & 127], 1);
    csr_src[row_start[d] + l] = (int)sd.x;
  }
}

// ---------------- BN constants ----------------
__global__ void k_prep_bn(const float* __restrict__ b, const float* __restrict__ g,
                          const float* __restrict__ be, const float* __restrict__ m,
                          const float* __restrict__ v, float* __restrict__ sc,
                          float* __restrict__ sh) {
  int f = threadIdx.x;
  if (f < FD) {
    float s = g[f] * rsqrtf(v[f] + BN_EPS);
    sc[f] = s;
    sh[f] = (b[f] - m[f]) * s + be[f];
  }
}

// ---------------- MFMA GEMM 128x128 (bf16x3 split) -> pre-scaled bf16 rows ----
// Hbs[row][n] = bf16( (X@W)[row][n] * dinv[row] ), row-major [N][128].
__global__ __launch_bounds__(256) void k_gemm128_mfma(const float* __restrict__ X,
                                                      const float* __restrict__ W,
                                                      const float* __restrict__ dinv,
                                                      unsigned short* __restrict__ Hbs,
                                                      int nrows) {
  __shared__ short bhi_s[FD * FD];  // 32 KB
  __shared__ short blo_s[FD * FD];  // 32 KB
  int tid = threadIdx.x;
  for (int i = tid; i < FD * FD; i += 256) {
    int k = i >> 7, n = i & 127;
    float w = W[i];
    unsigned short h = f2bf(w);
    unsigned short l = f2bf(w - bf2f(h));
    int idx = ((((k >> 5) * 8) + (n >> 4)) * 64 + ((k >> 3) & 3) * 16 + (n & 15)) * 8 + (k & 7);
    bhi_s[idx] = (short)h;
    blo_s[idx] = (short)l;
  }

  int lane = tid & 63, wv = tid >> 6;
  int lg = lane >> 4, li = lane & 15;
  int wr0 = blockIdx.x * 64 + wv * 16;
  int row = wr0 + li;
  bool ok = row < nrows;

  short8 ahi[4], alo[4];
#pragma unroll
  for (int ks = 0; ks < 4; ++ks) {
    if (ok) {
      const float* xp = X + (size_t)row * FD + ks * 32 + lg * 8;
      float4 v0 = *(const float4*)xp;
      float4 v1 = *(const float4*)(xp + 4);
      float f[8] = {v0.x, v0.y, v0.z, v0.w, v1.x, v1.y, v1.z, v1.w};
#pragma unroll
      for (int j = 0; j < 8; ++j) {
        unsigned short h = f2bf(f[j]);
        ahi[ks][j] = (short)h;
        alo[ks][j] = (short)f2bf(f[j] - bf2f(h));
      }
    } else {
#pragma unroll
      for (int j = 0; j < 8; ++j) { ahi[ks][j] = 0; alo[ks][j] = 0; }
    }
  }
  __syncthreads();

  int rb = wr0 + lg * 4;
  float dvr[4];
#pragma unroll
  for (int r = 0; r < 4; ++r) dvr[r] = (rb + r < nrows) ? dinv[rb + r] : 0.f;

#pragma unroll
  for (int nt = 0; nt < 8; ++nt) {
    f32x4 acc = {0.f, 0.f, 0.f, 0.f};
#pragma unroll
    for (int ks = 0; ks < 4; ++ks) {
      int bidx = ((ks * 8 + nt) * 64 + lane) * 8;
      short8 bh = *(const short8*)&bhi_s[bidx];
      short8 bl = *(const short8*)&blo_s[bidx];
      acc = __builtin_amdgcn_mfma_f32_16x16x32_bf16(ahi[ks], bh, acc, 0, 0, 0);
      acc = __builtin_amdgcn_mfma_f32_16x16x32_bf16(alo[ks], bh, acc, 0, 0, 0);
      acc = __builtin_amdgcn_mfma_f32_16x16x32_bf16(ahi[ks], bl, acc, 0, 0, 0);
    }
    // C/D: col = lane&15, row = (lane>>4)*4 + reg   [m89-verified]
    int col = nt * 16 + li;
#pragma unroll
    for (int r = 0; r < 4; ++r) {
      if (rb + r < nrows)
        Hbs[(size_t)(rb + r) * FD + col] = f2bf(acc[r] * dvr[r]);
    }
  }
}

// ---------------- node-parallel gather over pre-scaled bf16 rows ------------
// acc = (self row + sum of edge rows) * dinv[node]; rows pre-scaled by dinv[src].
template <bool BN>
__global__ __launch_bounds__(256) void k_gather128(const int* __restrict__ row_start,
                                                   const int* __restrict__ csr_src,
                                                   const float* __restrict__ dinv,
                                                   const unsigned short* __restrict__ Hbs,
                                                   const float* __restrict__ sc,
                                                   const float* __restrict__ sh,
                                                   float* __restrict__ AGG) {
  int node = blockIdx.x * 4 + (threadIdx.x >> 6);
  if (node >= NN) return;
  int lane = threadIdx.x & 63;
  const unsigned int* Hc = (const unsigned int*)Hbs;  // [N][64] packed bf16x2
  int beg = row_start[node], end = row_start[node + 1];
  unsigned int us = Hc[(size_t)node * 64 + lane];     // self row (pre-scaled)
  float ax = blo(us), ay = bhi(us);
  float bx = 0.f, by = 0.f, cx = 0.f, cy = 0.f, dx = 0.f, dy = 0.f;
  int e = beg;
  for (; e + 3 < end; e += 4) {
    int s0 = csr_src[e], s1 = csr_src[e + 1];
    int s2 = csr_src[e + 2], s3 = csr_src[e + 3];
    unsigned int u0 = Hc[(size_t)s0 * 64 + lane];
    unsigned int u1 = Hc[(size_t)s1 * 64 + lane];
    unsigned int u2 = Hc[(size_t)s2 * 64 + lane];
    unsigned int u3 = Hc[(size_t)s3 * 64 + lane];
    ax += blo(u0); ay += bhi(u0);
    bx += blo(u1); by += bhi(u1);
    cx += blo(u2); cy += bhi(u2);
    dx += blo(u3); dy += bhi(u3);
  }
  for (; e < end; ++e) {
    unsigned int u0 = Hc[(size_t)csr_src[e] * 64 + lane];
    ax += blo(u0); ay += bhi(u0);
  }
  float dv = dinv[node];
  float accx = ((ax + bx) + (cx + dx)) * dv;
  float accy = ((ay + by) + (cy + dy)) * dv;
  if (BN) {
    float scx = sc[lane * 2], scy = sc[lane * 2 + 1];
    float shx = sh[lane * 2], shy = sh[lane * 2 + 1];
    accx = fmaxf(fmaf(accx, scx, shx), 0.f);
    accy = fmaxf(fmaf(accy, scy, shy), 0.f);
  }
  float2 o; o.x = accx; o.y = accy;
  ((float2*)(AGG + (size_t)node * FD))[lane] = o;
}

// ---------------- output GEMM 128->10 ----------------
__global__ __launch_bounds__(256) void k_gemm_out(const float* __restrict__ X,
                                                  const float* __restrict__ W3,
                                                  float* __restrict__ H3, int nrows) {
  __shared__ float ws[FD * 16];
  int tid = threadIdx.x;
  for (int i = tid; i < FD * 16; i += 256) {
    int k = i >> 4, c = i & 15;
    ws[i] = (c < CO) ? W3[k * CO + c] : 0.f;
  }
  __syncthreads();
  int grp = tid >> 4;
  int c = tid & 15;
  int r = blockIdx.x * 16 + grp;
  if (r >= nrows) return;
  const float* x = X + (size_t)r * FD;
  float acc = 0.f;
#pragma unroll
  for (int k = 0; k < FD; k += 4) {
    float4 xv = *(const float4*)&x[k];
    acc += xv.x * ws[(k + 0) * 16 + c];
    acc += xv.y * ws[(k + 1) * 16 + c];
    acc += xv.z * ws[(k + 2) * 16 + c];
    acc += xv.w * ws[(k + 3) * 16 + c];
  }
  if (c < CO) H3[(size_t)r * CO + c] = acc;
}

// ---------------- gather 10 feat, fused self-loop + bias, writes out --------
__global__ __launch_bounds__(256) void k_gather10(const int* __restrict__ row_start,
                                                  const int* __restrict__ csr_src,
                                                  const float* __restrict__ dinv,
                                                  const float* __restrict__ H3,
                                                  const float* __restrict__ b3,
                                                  float* __restrict__ out) {
  int node = blockIdx.x * 16 + (threadIdx.x >> 4);
  if (node >= NN) return;
  int c = threadIdx.x & 15;
  int beg = row_start[node], end = row_start[node + 1];
  float dv = dinv[node];
  float acc = 0.f;
  if (c < CO) acc = H3[(size_t)node * CO + c] * (dv * dv);
  for (int e = beg; e < end; ++e) {
    int s = csr_src[e];
    float cf = dinv[s] * dv;
    if (c < CO) acc = fmaf(H3[(size_t)s * CO + c], cf, acc);
  }
  if (c < CO) out[(size_t)node * CO + c] = acc + b3[c];
}

// ---------------- launch ----------------
extern "C" void kernel_launch(void* const* d_in, const int* in_sizes, int n_in,
                              void* d_out, int out_size, void* d_ws, size_t ws_size,
                              hipStream_t stream) {
  const float* x = (const float*)d_in[0];
  const int* src = (const int*)d_in[1];
  const int* dst = (const int*)d_in[2];
  const float* W1 = (const float*)d_in[3];
  const float* b1 = (const float*)d_in[4];
  const float* g1 = (const float*)d_in[5];
  const float* be1 = (const float*)d_in[6];
  const float* m1 = (const float*)d_in[7];
  const float* v1 = (const float*)d_in[8];
  const float* W2 = (const float*)d_in[9];
  const float* b2 = (const float*)d_in[10];
  const float* g2 = (const float*)d_in[11];
  const float* be2 = (const float*)d_in[12];
  const float* m2 = (const float*)d_in[13];
  const float* v2 = (const float*)d_in[14];
  const float* W3 = (const float*)d_in[15];
  const float* b3 = (const float*)d_in[16];
  float* out = (float*)d_out;

  char* wsb = (char*)d_ws;
  int* deg_i = (int*)wsb;                     wsb += NN * 4;
  int* row_start = (int*)wsb;                 wsb += (NN + 1) * 4;
  int* bcnt = (int*)wsb;                      wsb += (size_t)NBUK * 16 * 4;
  int* blocksum = (int*)wsb;                  wsb += 128 * 4;
  float* dinv = (float*)wsb;                  wsb += NN * 4;
  float* sc1 = (float*)wsb;                   wsb += FD * 4;
  float* sh1 = (float*)wsb;                   wsb += FD * 4;
  float* sc2 = (float*)wsb;                   wsb += FD * 4;
  float* sh2 = (float*)wsb;                   wsb += FD * 4;
  int* csr_src = (int*)wsb;                   wsb += (size_t)NE * 4;
  uint2* buck = (uint2*)wsb;                  wsb += (size_t)NBUK * BCAP * 8;
  float* AGG = (float*)wsb;                   wsb += (size_t)NN * FD * 4;   // [N][128] f32
  unsigned short* Hbs = (unsigned short*)wsb; wsb += (size_t)NN * FD * 2;   // [N][128] bf16
  float* H3 = (float*)Hbs;  // layer-3 reuse (Hbs dead after layer-2 gather)

  hipMemsetAsync(bcnt, 0, (size_t)NBUK * 16 * 4, stream);
  k_bucket2<<<NSEG, 256, 0, stream>>>(src, dst, bcnt, buck);
  k_bdeg<<<NBUK, 256, 0, stream>>>(bcnt, buck, deg_i, dinv);
  k_scan_partial<<<SCAN_NB, 256, 0, stream>>>(deg_i, blocksum);
  k_scan_block<<<1, 128, 0, stream>>>(blocksum);
  k_scan_final<<<SCAN_NB, 256, 0, stream>>>(deg_i, blocksum, row_start);
  k_place<<<NBUK, 256, 0, stream>>>(bcnt, buck, row_start, csr_src);
  k_prep_bn<<<1, 128, 0, stream>>>(b1, g1, be1, m1, v1, sc1, sh1);
  k_prep_bn<<<1, 128, 0, stream>>>(b2, g2, be2, m2, v2, sc2, sh2);

  int gemm_blocks = (NN + 63) / 64;
  int gat_blocks = (NN + 3) / 4;

  // layer 1
  k_gemm128_mfma<<<gemm_blocks, 256, 0, stream>>>(x, W1, dinv, Hbs, NN);
  k_gather128<true><<<gat_blocks, 256, 0, stream>>>(row_start, csr_src, dinv,
                                                    Hbs, sc1, sh1, AGG);
  // layer 2
  k_gemm128_mfma<<<gemm_blocks, 256, 0, stream>>>(AGG, W2, dinv, Hbs, NN);
  k_gather128<true><<<gat_blocks, 256, 0, stream>>>(row_start, csr_src, dinv,
                                                    Hbs, sc2, sh2, AGG);
  // layer 3
  k_gemm_out<<<(NN + 15) / 16, 256, 0, stream>>>(AGG, W3, H3, NN);
  k_gather10<<<(NN + 15) / 16, 256, 0, stream>>>(row_start, csr_src, dinv,
                                                 H3, b3, out);
}